// Round 10
// baseline (873.312 us; speedup 1.0000x reference)
//
#include <hip/hip_runtime.h>

#define NN 100000   // nodes
#define NE 500000   // edges per relation
#define NR 4        // relations
#define NL 4        // layers
#define FIN 64      // input features
#define D 128       // embedding dim
#define NGR 64      // graphs

#define FP 8        // dst partitions (XCD round-robin heuristic)
#define PSZ ((NN + FP - 1) / FP)   // 12500 nodes per partition
#define EPB 4096    // edges per block chunk in slot_fill
#define CAPS 16     // slot capacity; overflow -> tiny global list
#define OVFCAP 8192 // overflow entries (expected ~10; P(deg>16|Poisson(5))~3e-5)

typedef __attribute__((ext_vector_type(8))) short short8;
typedef __attribute__((ext_vector_type(4))) float f32x4;
typedef __attribute__((ext_vector_type(2))) unsigned short u16x2;
typedef unsigned short ushort;
typedef unsigned int uint;

__device__ __forceinline__ ushort f2b(float f) {
    uint u = __float_as_uint(f);
    uint r = (u + 0x7fffu + ((u >> 16) & 1u)) >> 16;  // RNE
    return (ushort)r;
}
__device__ __forceinline__ float b2f(ushort b) {
    return __uint_as_float(((uint)b) << 16);
}
// monotone bf16 -> u16 key (order-isomorphic bijection); key 0 = -inf sentinel
__device__ __forceinline__ ushort enc16(ushort u) {
    return u ^ (ushort)((((short)u) >> 15) | (short)0x8000);
}
__device__ __forceinline__ ushort dec16(ushort k) {
    return k ^ (ushort)((((short)(k ^ 0x8000)) >> 15) | (short)0x8000);
}
__device__ __forceinline__ u16x2 vmax2(u16x2 a, u16x2 b) {
#if __has_builtin(__builtin_elementwise_max)
    return __builtin_elementwise_max(a, b);
#else
    u16x2 r;
    r.x = a.x > b.x ? a.x : b.x;
    r.y = a.y > b.y ? a.y : b.y;
    return r;
#endif
}

// ---------------- utility ----------------
__global__ void zero_i32(int* __restrict__ p, int n) {
    int i = blockIdx.x * blockDim.x + threadIdx.x;
    if (i < n) p[i] = 0;
}
__global__ void zero_f32(float* __restrict__ p, int n) {
    int i = blockIdx.x * blockDim.x + threadIdx.x;
    if (i < n) p[i] = 0.f;
}
__global__ void xcvt(const float* __restrict__ x, ushort* __restrict__ xb, int n) {
    int i = blockIdx.x * blockDim.x + threadIdx.x;
    if (i < n) xb[i] = f2b(x[i]);
}
// zero the dummy row (index NN) of each of the G m-buffers (stride (NN+1)*D)
__global__ void zero_dummy(ushort* __restrict__ mbuf, int G) {
    int i = blockIdx.x * blockDim.x + threadIdx.x;
    if (i < G * D)
        mbuf[(size_t)(i / D) * (NN + 1) * D + (size_t)NN * D + (i % D)] = 0;
}

// W fp32 [nmat][K x 128] -> MFMA fragment order (works as either operand:
// stored[(t*K032+k0)*64 + lane][j] = W[k0*32 + (lane>>4)*8 + j][t*16 + (lane&15)];
// interpreted as operand-A it is W^T[i=lane&15][k=quad*8+j] for feature tile t).
__global__ void wperm_kernel(const float* __restrict__ W, ushort* __restrict__ dst,
                             int K, int total) {
    int i = blockIdx.x * blockDim.x + threadIdx.x;
    if (i >= total) return;
    int per = K * 128;
    int mi = i / per;
    int o = i - mi * per;
    int j = o & 7, lane = (o >> 3) & 63, rest = o >> 9;
    int K032 = K / 32;
    int k0 = rest % K032, t = rest / K032;
    int k = k0 * 32 + (lane >> 4) * 8 + j;
    int n = t * 16 + (lane & 15);
    dst[i] = f2b(W[(size_t)mi * per + k * 128 + n]);
}

// ---------------- one-pass slotted adjacency build, XCD-partitioned ----------------
__global__ __launch_bounds__(256) void slot_fill(const int* __restrict__ e0,
                                                 const int* __restrict__ e1,
                                                 const int* __restrict__ e2,
                                                 const int* __restrict__ e3,
                                                 int* __restrict__ deg,
                                                 int* __restrict__ slots,
                                                 int* __restrict__ ovf_cnt,
                                                 int* __restrict__ ovf) {
    const int part = blockIdx.x % FP;
    const int chunk = blockIdx.x / FP;
    const int plo = part * PSZ;
    const int phi = (plo + PSZ < NN) ? plo + PSZ : NN;
    const int i0 = chunk * EPB;
    int i1 = i0 + EPB; if (i1 > NR * NE) i1 = NR * NE;
    for (int i = i0 + threadIdx.x; i < i1; i += 256) {
        int r = i / NE, j = i - r * NE;
        const int* ei = (r == 0) ? e0 : (r == 1) ? e1 : (r == 2) ? e2 : e3;
        int d = __builtin_nontemporal_load(&ei[NE + j]);
        if (d >= plo && d < phi) {
            int s = __builtin_nontemporal_load(&ei[j]);
            int slot = atomicAdd(&deg[d * NR + r], 1);
            if (slot < CAPS) {
                slots[((size_t)d * NR + r) * CAPS + slot] = s * (D * 2);
            } else {
                int oi = atomicAdd(ovf_cnt, 1);
                if (oi < OVFCAP) {
                    ovf[2 * oi] = d * NR + r;
                    ovf[2 * oi + 1] = s * (D * 2);
                }
            }
        }
    }
}

// ---------------- bf16 MFMA GEMM, operand-swapped (weights = operand A) ----------------
// D[feat][node]: per lane node = lane&15, feats = ftile*16 + quad*4 + (0..3)
// -> 4 consecutive bf16 per lane = one 8B store. MODE 1: monotone key16 output.
template <int K, int MODE>
__global__ __launch_bounds__(256) void mgemm(const ushort* __restrict__ A,
                                             const ushort* __restrict__ Bp,
                                             const float* __restrict__ bias,
                                             ushort* __restrict__ Ch) {
    constexpr int K032 = K / 32;
    __shared__ ushort Bs[8 * K032 * 64 * 8];
    const int tid = threadIdx.x;
    for (int i = tid; i < K * 16; i += 256)
        ((float4*)Bs)[i] = ((const float4*)Bp)[i];
    const int lane = tid & 63, wave = tid >> 6;
    const int quad = lane >> 4, l15 = lane & 15;
    const int ch = wave >> 1;  // feature half: ftiles ch*4 .. ch*4+3
    const int ng = wave & 1;   // node 16-tile within 32-node block tile
    __syncthreads();
    short8 breg[4][K032];
#pragma unroll
    for (int tt = 0; tt < 4; tt++)
#pragma unroll
        for (int k0 = 0; k0 < K032; k0++)
            breg[tt][k0] = *(const short8*)&Bs[(size_t)(((ch * 4 + tt) * K032 + k0) * 64 + lane) * 8];
    float bv[4][4];
#pragma unroll
    for (int tt = 0; tt < 4; tt++)
#pragma unroll
        for (int r = 0; r < 4; r++)
            bv[tt][r] = bias ? bias[(ch * 4 + tt) * 16 + quad * 4 + r] : 0.f;
    for (int tile = blockIdx.x; tile < NN / 32; tile += gridDim.x) {
        const int node = tile * 32 + ng * 16 + l15;
        const ushort* Ar = A + (size_t)node * K + quad * 8;
        short8 a[K032];
#pragma unroll
        for (int k0 = 0; k0 < K032; k0++) a[k0] = *(const short8*)(Ar + k0 * 32);
        f32x4 acc[4];
#pragma unroll
        for (int tt = 0; tt < 4; tt++)
            acc[tt] = (f32x4){bv[tt][0], bv[tt][1], bv[tt][2], bv[tt][3]};
#pragma unroll
        for (int k0 = 0; k0 < K032; k0++)
#pragma unroll
            for (int tt = 0; tt < 4; tt++)
                acc[tt] = __builtin_amdgcn_mfma_f32_16x16x32_bf16(breg[tt][k0], a[k0], acc[tt], 0, 0, 0);
#pragma unroll
        for (int tt = 0; tt < 4; tt++) {
            ushort v0 = f2b(acc[tt][0]), v1 = f2b(acc[tt][1]);
            ushort v2 = f2b(acc[tt][2]), v3 = f2b(acc[tt][3]);
            if (MODE == 1) { v0 = enc16(v0); v1 = enc16(v1); v2 = enc16(v2); v3 = enc16(v3); }
            uint2 pk = make_uint2((uint)v0 | ((uint)v1 << 16), (uint)v2 | ((uint)v3 << 16));
            *(uint2*)&Ch[(size_t)node * D + (ch * 4 + tt) * 16 + quad * 4] = pk;
        }
    }
}

// ---------------- fused per-layer GEMM: blockIdx.y = matrix (0=root, 1..4=conv r) ----------------
__global__ __launch_bounds__(256) void mgemm5(const ushort* __restrict__ A,
                                              const ushort* __restrict__ wpRootL,
                                              const ushort* __restrict__ wpConvL,
                                              const float* __restrict__ biasL,
                                              ushort* __restrict__ ob,
                                              ushort* __restrict__ mbuf) {
    constexpr int K032 = 4;  // K=128
    const int m = blockIdx.y;
    const ushort* Bp = (m == 0) ? wpRootL : wpConvL + (size_t)(m - 1) * 128 * 128;
    ushort* Ch = (m == 0) ? ob : mbuf + (size_t)(m - 1) * (NN + 1) * D;
    const bool key = (m != 0);
    __shared__ ushort Bs[8 * K032 * 64 * 8];
    const int tid = threadIdx.x;
    for (int i = tid; i < 128 * 16; i += 256)
        ((float4*)Bs)[i] = ((const float4*)Bp)[i];
    const int lane = tid & 63, wave = tid >> 6;
    const int quad = lane >> 4, l15 = lane & 15;
    const int ch = wave >> 1;
    const int ng = wave & 1;
    __syncthreads();
    short8 breg[4][K032];
#pragma unroll
    for (int tt = 0; tt < 4; tt++)
#pragma unroll
        for (int k0 = 0; k0 < K032; k0++)
            breg[tt][k0] = *(const short8*)&Bs[(size_t)(((ch * 4 + tt) * K032 + k0) * 64 + lane) * 8];
    float bv[4][4];
#pragma unroll
    for (int tt = 0; tt < 4; tt++)
#pragma unroll
        for (int r = 0; r < 4; r++)
            bv[tt][r] = (m == 0) ? biasL[(ch * 4 + tt) * 16 + quad * 4 + r] : 0.f;
    for (int tile = blockIdx.x; tile < NN / 32; tile += gridDim.x) {
        const int node = tile * 32 + ng * 16 + l15;
        const ushort* Ar = A + (size_t)node * 128 + quad * 8;
        short8 a[K032];
#pragma unroll
        for (int k0 = 0; k0 < K032; k0++) a[k0] = *(const short8*)(Ar + k0 * 32);
        f32x4 acc[4];
#pragma unroll
        for (int tt = 0; tt < 4; tt++)
            acc[tt] = (f32x4){bv[tt][0], bv[tt][1], bv[tt][2], bv[tt][3]};
#pragma unroll
        for (int k0 = 0; k0 < K032; k0++)
#pragma unroll
            for (int tt = 0; tt < 4; tt++)
                acc[tt] = __builtin_amdgcn_mfma_f32_16x16x32_bf16(breg[tt][k0], a[k0], acc[tt], 0, 0, 0);
#pragma unroll
        for (int tt = 0; tt < 4; tt++) {
            ushort v0 = f2b(acc[tt][0]), v1 = f2b(acc[tt][1]);
            ushort v2 = f2b(acc[tt][2]), v3 = f2b(acc[tt][3]);
            if (key) { v0 = enc16(v0); v1 = enc16(v1); v2 = enc16(v2); v3 = enc16(v3); }
            uint2 pk = make_uint2((uint)v0 | ((uint)v1 << 16), (uint)v2 | ((uint)v3 << 16));
            *(uint2*)&Ch[(size_t)node * D + (ch * 4 + tt) * 16 + quad * 4] = pk;
        }
    }
}

// ---------------- interleaved multi-relation scatter-max, 4-wide unrolled ----------------
template <int G>
__global__ __launch_bounds__(256) void agg_kernel(const ushort* __restrict__ mb,
                                                  const int* __restrict__ deg,
                                                  const int* __restrict__ slots,
                                                  const int* __restrict__ ovf_cnt,
                                                  const int* __restrict__ ovf,
                                                  int g0,
                                                  const ushort* __restrict__ base,
                                                  ushort* __restrict__ outh,
                                                  int do_relu) {
    const int wv = threadIdx.x >> 6;
    const int lane = threadIdx.x & 63;
    const int node = blockIdx.x * 4 + wv;
    if (node >= NN) return;
    const int DUM = NN * D * 2;  // byte offset of dummy row
    const int* db = deg + (size_t)node * NR + g0;
    const int* sb = slots + ((size_t)node * NR + g0) * CAPS;
    int nd[G], s_l[G];
    const char* ml[G];
#pragma unroll
    for (int g = 0; g < G; g++) {
        int n = db[g];
        nd[g] = (n > CAPS) ? CAPS : n;
        s_l[g] = (lane < nd[g]) ? sb[g * CAPS + lane] : DUM;
        ml[g] = (const char*)(mb + (size_t)g * (NN + 1) * D) + lane * 4;
    }
    int ndmax = 0;
#pragma unroll
    for (int g = 0; g < G; g++) ndmax = (nd[g] > ndmax) ? nd[g] : ndmax;
    u16x2 acc[G];
#pragma unroll
    for (int g = 0; g < G; g++) acc[g] = (u16x2)0;
    for (int i = 0; i < ndmax; i += 4) {
        int s[G][4];
#pragma unroll
        for (int g = 0; g < G; g++) {
#pragma unroll
            for (int u = 0; u < 4; u++) {
                int sv = __shfl(s_l[g], i + u);
                s[g][u] = (i + u < nd[g]) ? sv : DUM;
            }
        }
#pragma unroll
        for (int g = 0; g < G; g++) {
            u16x2 v0 = *(const u16x2*)(ml[g] + s[g][0]);
            u16x2 v1 = *(const u16x2*)(ml[g] + s[g][1]);
            u16x2 v2 = *(const u16x2*)(ml[g] + s[g][2]);
            u16x2 v3 = *(const u16x2*)(ml[g] + s[g][3]);
            acc[g] = vmax2(acc[g], vmax2(vmax2(v0, v1), vmax2(v2, v3)));
        }
    }
    // rare overflow edges (deg > CAPS): wave-uniform scan of tiny list
    int novf = *ovf_cnt;
    if (novf > OVFCAP) novf = OVFCAP;
    for (int i = 0; i < novf; i++) {
        int edr = ovf[2 * i];
        int dr = edr - (node * NR + g0);
        if (dr >= 0 && dr < G) {
            int so = ovf[2 * i + 1];
#pragma unroll
            for (int g = 0; g < G; g++)
                if (dr == g)
                    acc[g] = vmax2(acc[g], *(const u16x2*)(ml[g] + so));
        }
    }
    uint bp = ((const uint*)(base + (size_t)node * D))[lane];
    float rx = __uint_as_float(bp << 16), ry = __uint_as_float(bp & 0xffff0000u);
#pragma unroll
    for (int g = 0; g < G; g++) {
        rx += (nd[g] > 0) ? b2f(dec16(acc[g].x)) : 0.f;
        ry += (nd[g] > 0) ? b2f(dec16(acc[g].y)) : 0.f;
    }
    if (do_relu) { rx = fmaxf(rx, 0.f); ry = fmaxf(ry, 0.f); }
    uint pk = (uint)f2b(rx) | ((uint)f2b(ry) << 16);
    ((uint*)(outh + (size_t)node * D))[lane] = pk;
}

// ---------------- global add pool (batch sorted), h in bf16 ----------------
#define PCH 256
__global__ __launch_bounds__(128) void pool_kernel(const ushort* __restrict__ h,
                                                   const int* __restrict__ batch,
                                                   float* __restrict__ out) {
    int c = threadIdx.x;
    int n0 = blockIdx.x * PCH;
    if (n0 >= NN) return;
    int n1 = n0 + PCH; if (n1 > NN) n1 = NN;
    int cur = batch[n0];
    float acc = 0.f;
    for (int n = n0; n < n1; n++) {
        int g = batch[n];
        if (g != cur) {
            atomicAdd(&out[cur * D + c], acc);
            acc = 0.f;
            cur = g;
        }
        acc += b2f(h[(size_t)n * D + c]);
    }
    atomicAdd(&out[cur * D + c], acc);
}

extern "C" void kernel_launch(void* const* d_in, const int* in_sizes, int n_in,
                              void* d_out, int out_size, void* d_ws, size_t ws_size,
                              hipStream_t stream) {
    const float* x = (const float*)d_in[0];
    const int* ei[4] = {(const int*)d_in[1], (const int*)d_in[2],
                        (const int*)d_in[3], (const int*)d_in[4]};
    const int* batch = (const int*)d_in[5];
    const float* emb_w = (const float*)d_in[6];
    const float* emb_b = (const float*)d_in[7];
    const float* root_w = (const float*)d_in[8];
    const float* root_b = (const float*)d_in[9];
    const float* conv_w = (const float*)d_in[10];
    float* out = (float*)d_out;

    const size_t WPT = (size_t)FIN * 128 + 20 * (size_t)128 * 128;  // permuted weights
    const size_t intWords = (size_t)NR * NN * (1 + CAPS) + 1 + 2 * OVFCAP;
    // choose G by ws capacity (ws_size constant across calls -> same path every launch)
    int G = 1;
    for (int g = 4; g >= 1; g >>= 1) {
        size_t need = ((size_t)NN * D * 2 + (size_t)g * (NN + 1) * D + (size_t)NN * FIN + WPT) * 2 +
                      intWords * 4;
        if (ws_size >= need) { G = g; break; }
    }

    // workspace layout
    ushort* hb = (ushort*)d_ws;                          // NN*D
    ushort* ob = hb + (size_t)NN * D;                    // NN*D (base)
    ushort* mbuf = ob + (size_t)NN * D;                  // G*(NN+1)*D (key16, +dummy row)
    ushort* xb = mbuf + (size_t)G * (NN + 1) * D;        // NN*FIN
    ushort* wp = xb + (size_t)NN * FIN;                  // WPT
    int* deg = (int*)(wp + WPT);                         // NN*NR  (node-major)
    int* ovf_cnt = deg + (size_t)NR * NN;                // 1
    int* slots = ovf_cnt + 1;                            // NN*NR*CAPS (src byte-offsets)
    int* ovf = slots + (size_t)NR * NN * CAPS;           // 2*OVFCAP
    ushort* wpEmb = wp;
    ushort* wpRoot = wp + (size_t)FIN * 128;
    ushort* wpConv = wpRoot + (size_t)4 * 128 * 128;

    // ---- adjacency build: zero deg+ovf_cnt + one-pass partitioned slot fill ----
    zero_i32<<<(NR * NN + 1 + 255) / 256, 256, 0, stream>>>(deg, NR * NN + 1);
    {
        int nch = (NR * NE + EPB - 1) / EPB;
        slot_fill<<<nch * FP, 256, 0, stream>>>(ei[0], ei[1], ei[2], ei[3],
                                                deg, slots, ovf_cnt, ovf);
    }

    // ---- weight permute + input convert + dummy rows ----
    {
        int t1 = FIN * 128;
        wperm_kernel<<<(t1 + 255) / 256, 256, 0, stream>>>(emb_w, wpEmb, FIN, t1);
        int t2 = 4 * 128 * 128;
        wperm_kernel<<<(t2 + 255) / 256, 256, 0, stream>>>(root_w, wpRoot, 128, t2);
        int t3 = 16 * 128 * 128;
        wperm_kernel<<<(t3 + 255) / 256, 256, 0, stream>>>(conv_w, wpConv, 128, t3);
        int t4 = NN * FIN;
        xcvt<<<(t4 + 255) / 256, 256, 0, stream>>>(x, xb, t4);
        zero_dummy<<<(G * D + 255) / 256, 256, 0, stream>>>(mbuf, G);
    }

    // ---- embedding ----
    mgemm<FIN, 0><<<1024, 256, 0, stream>>>(xb, wpEmb, emb_b, hb);

    // ---- layers ----
    for (int l = 0; l < NL; l++) {
        if (G == 4) {
            mgemm5<<<dim3(640, 5), 256, 0, stream>>>(hb, wpRoot + (size_t)l * 128 * 128,
                                                     wpConv + (size_t)l * 4 * 128 * 128,
                                                     root_b + (size_t)l * D, ob, mbuf);
            agg_kernel<4><<<(NN + 3) / 4, 256, 0, stream>>>(mbuf, deg, slots, ovf_cnt, ovf,
                                                            0, ob, hb, 1);
        } else {
            mgemm<128, 0><<<1024, 256, 0, stream>>>(hb, wpRoot + (size_t)l * 128 * 128,
                                                    root_b + (size_t)l * D, ob);
            for (int g0 = 0; g0 < NR; g0 += G) {
                for (int r = g0; r < g0 + G; r++)
                    mgemm<128, 1><<<1024, 256, 0, stream>>>(
                        hb, wpConv + (size_t)(l * NR + r) * 128 * 128, nullptr,
                        mbuf + (size_t)(r - g0) * (NN + 1) * D);
                int last = (g0 + G == NR);
                if (G == 2)
                    agg_kernel<2><<<(NN + 3) / 4, 256, 0, stream>>>(
                        mbuf, deg, slots, ovf_cnt, ovf, g0, ob, last ? hb : ob, last ? 1 : 0);
                else
                    agg_kernel<1><<<(NN + 3) / 4, 256, 0, stream>>>(
                        mbuf, deg, slots, ovf_cnt, ovf, g0, ob, last ? hb : ob, last ? 1 : 0);
            }
        }
    }

    // ---- global add pool ----
    zero_f32<<<(NGR * D + 255) / 256, 256, 0, stream>>>(out, NGR * D);
    pool_kernel<<<(NN + PCH - 1) / PCH, 128, 0, stream>>>(hb, batch, out);
}

// Round 11
// 832.289 us; speedup vs baseline: 1.0493x; 1.0493x over previous
//
#include <hip/hip_runtime.h>

#define NN 100000   // nodes
#define NE 500000   // edges per relation
#define NR 4        // relations
#define NL 4        // layers
#define FIN 64      // input features
#define D 128       // embedding dim
#define NGR 64      // graphs

#define FP 8        // dst partitions (XCD round-robin heuristic)
#define PSZ ((NN + FP - 1) / FP)   // 12500 nodes per partition
#define EPB 4096    // edges per block chunk in slot_fill
#define CAPS 16     // slot capacity; overflow -> tiny global list
#define OVFCAP 8192 // overflow entries (expected ~10; P(deg>16|Poisson(5))~3e-5)

typedef __attribute__((ext_vector_type(8))) short short8;
typedef __attribute__((ext_vector_type(4))) float f32x4;
typedef __attribute__((ext_vector_type(2))) unsigned short u16x2;
typedef unsigned short ushort;
typedef unsigned int uint;

__device__ __forceinline__ ushort f2b(float f) {
    uint u = __float_as_uint(f);
    uint r = (u + 0x7fffu + ((u >> 16) & 1u)) >> 16;  // RNE
    return (ushort)r;
}
__device__ __forceinline__ float b2f(ushort b) {
    return __uint_as_float(((uint)b) << 16);
}
// monotone bf16 -> u16 key (order-isomorphic bijection); key 0 = -inf sentinel
__device__ __forceinline__ ushort enc16(ushort u) {
    return u ^ (ushort)((((short)u) >> 15) | (short)0x8000);
}
__device__ __forceinline__ ushort dec16(ushort k) {
    return k ^ (ushort)((((short)(k ^ 0x8000)) >> 15) | (short)0x8000);
}
__device__ __forceinline__ u16x2 vmax2(u16x2 a, u16x2 b) {
#if __has_builtin(__builtin_elementwise_max)
    return __builtin_elementwise_max(a, b);
#else
    u16x2 r;
    r.x = a.x > b.x ? a.x : b.x;
    r.y = a.y > b.y ? a.y : b.y;
    return r;
#endif
}

// ---------------- utility ----------------
__global__ void zero_i32(int* __restrict__ p, int n) {
    int i = blockIdx.x * blockDim.x + threadIdx.x;
    if (i < n) p[i] = 0;
}
__global__ void zero_f32(float* __restrict__ p, int n) {
    int i = blockIdx.x * blockDim.x + threadIdx.x;
    if (i < n) p[i] = 0.f;
}
__global__ void xcvt(const float* __restrict__ x, ushort* __restrict__ xb, int n) {
    int i = blockIdx.x * blockDim.x + threadIdx.x;
    if (i < n) xb[i] = f2b(x[i]);
}
// zero the dummy row (index NN) of each of the G m-buffers (stride (NN+1)*D)
__global__ void zero_dummy(ushort* __restrict__ mbuf, int G) {
    int i = blockIdx.x * blockDim.x + threadIdx.x;
    if (i < G * D)
        mbuf[(size_t)(i / D) * (NN + 1) * D + (size_t)NN * D + (i % D)] = 0;
}

// W fp32 [nmat][K x 128] -> bf16 MFMA B-fragment order
__global__ void wperm_kernel(const float* __restrict__ W, ushort* __restrict__ dst,
                             int K, int total) {
    int i = blockIdx.x * blockDim.x + threadIdx.x;
    if (i >= total) return;
    int per = K * 128;
    int mi = i / per;
    int o = i - mi * per;
    int j = o & 7, lane = (o >> 3) & 63, rest = o >> 9;
    int K032 = K / 32;
    int k0 = rest % K032, t = rest / K032;
    int k = k0 * 32 + (lane >> 4) * 8 + j;
    int n = t * 16 + (lane & 15);
    dst[i] = f2b(W[(size_t)mi * per + k * 128 + n]);
}

// ---------------- one-pass slotted adjacency build, XCD-partitioned ----------------
__global__ __launch_bounds__(256) void slot_fill(const int* __restrict__ e0,
                                                 const int* __restrict__ e1,
                                                 const int* __restrict__ e2,
                                                 const int* __restrict__ e3,
                                                 int* __restrict__ deg,
                                                 int* __restrict__ slots,
                                                 int* __restrict__ ovf_cnt,
                                                 int* __restrict__ ovf) {
    const int part = blockIdx.x % FP;
    const int chunk = blockIdx.x / FP;
    const int plo = part * PSZ;
    const int phi = (plo + PSZ < NN) ? plo + PSZ : NN;
    const int i0 = chunk * EPB;
    int i1 = i0 + EPB; if (i1 > NR * NE) i1 = NR * NE;
    for (int i = i0 + threadIdx.x; i < i1; i += 256) {
        int r = i / NE, j = i - r * NE;
        const int* ei = (r == 0) ? e0 : (r == 1) ? e1 : (r == 2) ? e2 : e3;
        int d = __builtin_nontemporal_load(&ei[NE + j]);
        if (d >= plo && d < phi) {
            int s = __builtin_nontemporal_load(&ei[j]);
            int slot = atomicAdd(&deg[d * NR + r], 1);
            if (slot < CAPS) {
                slots[((size_t)d * NR + r) * CAPS + slot] = s * (D * 2);
            } else {
                int oi = atomicAdd(ovf_cnt, 1);
                if (oi < OVFCAP) {
                    ovf[2 * oi] = d * NR + r;
                    ovf[2 * oi + 1] = s * (D * 2);
                }
            }
        }
    }
}

// ---------------- bf16 MFMA GEMM (h rows = operand A; R9-verified layout) ----------------
template <int K, int MODE>
__global__ __launch_bounds__(256) void mgemm(const ushort* __restrict__ A,
                                             const ushort* __restrict__ Bp,
                                             const float* __restrict__ bias,
                                             ushort* __restrict__ Ch) {
    constexpr int K032 = K / 32;
    __shared__ ushort Bs[8 * K032 * 64 * 8];
    const int tid = threadIdx.x;
    for (int i = tid; i < K * 16; i += 256)
        ((float4*)Bs)[i] = ((const float4*)Bp)[i];
    const int lane = tid & 63, wave = tid >> 6;
    const int quad = lane >> 4, l15 = lane & 15;
    const int ch = wave & 1, rg = wave >> 1;
    __syncthreads();
    short8 breg[4][K032];
#pragma unroll
    for (int tt = 0; tt < 4; tt++)
#pragma unroll
        for (int k0 = 0; k0 < K032; k0++)
            breg[tt][k0] = *(const short8*)&Bs[(size_t)(((ch * 4 + tt) * K032 + k0) * 64 + lane) * 8];
    float bv[4] = {0.f, 0.f, 0.f, 0.f};
    if (bias)
#pragma unroll
        for (int tt = 0; tt < 4; tt++) bv[tt] = bias[(ch * 4 + tt) * 16 + l15];
    for (int tile = blockIdx.x; tile < NN / 32; tile += gridDim.x) {
        const int row0 = tile * 32 + rg * 16;
        const ushort* Ar = A + (size_t)(row0 + l15) * K + quad * 8;
        short8 a[K032];
#pragma unroll
        for (int k0 = 0; k0 < K032; k0++) a[k0] = *(const short8*)(Ar + k0 * 32);
        f32x4 acc[4];
#pragma unroll
        for (int tt = 0; tt < 4; tt++) acc[tt] = (f32x4){bv[tt], bv[tt], bv[tt], bv[tt]};
#pragma unroll
        for (int k0 = 0; k0 < K032; k0++)
#pragma unroll
            for (int tt = 0; tt < 4; tt++)
                acc[tt] = __builtin_amdgcn_mfma_f32_16x16x32_bf16(a[k0], breg[tt][k0], acc[tt], 0, 0, 0);
#pragma unroll
        for (int tt = 0; tt < 4; tt++) {
            const int col = (ch * 4 + tt) * 16 + l15;
#pragma unroll
            for (int r = 0; r < 4; r++) {
                ushort v = f2b(acc[tt][r]);
                if (MODE == 1) v = enc16(v);
                Ch[(size_t)(row0 + quad * 4 + r) * D + col] = v;
            }
        }
    }
}

// ---------------- fused per-layer GEMM: blockIdx.y = matrix (0=root, 1..4=conv r) ----------------
__global__ __launch_bounds__(256) void mgemm5(const ushort* __restrict__ A,
                                              const ushort* __restrict__ wpRootL,
                                              const ushort* __restrict__ wpConvL,
                                              const float* __restrict__ biasL,
                                              ushort* __restrict__ ob,
                                              ushort* __restrict__ mbuf) {
    constexpr int K032 = 4;  // K=128
    const int m = blockIdx.y;
    const ushort* Bp = (m == 0) ? wpRootL : wpConvL + (size_t)(m - 1) * 128 * 128;
    ushort* Ch = (m == 0) ? ob : mbuf + (size_t)(m - 1) * (NN + 1) * D;
    const bool key = (m != 0);
    __shared__ ushort Bs[8 * K032 * 64 * 8];
    const int tid = threadIdx.x;
    for (int i = tid; i < 128 * 16; i += 256)
        ((float4*)Bs)[i] = ((const float4*)Bp)[i];
    const int lane = tid & 63, wave = tid >> 6;
    const int quad = lane >> 4, l15 = lane & 15;
    const int ch = wave & 1, rg = wave >> 1;
    __syncthreads();
    short8 breg[4][K032];
#pragma unroll
    for (int tt = 0; tt < 4; tt++)
#pragma unroll
        for (int k0 = 0; k0 < K032; k0++)
            breg[tt][k0] = *(const short8*)&Bs[(size_t)(((ch * 4 + tt) * K032 + k0) * 64 + lane) * 8];
    float bv[4] = {0.f, 0.f, 0.f, 0.f};
    if (m == 0)
#pragma unroll
        for (int tt = 0; tt < 4; tt++) bv[tt] = biasL[(ch * 4 + tt) * 16 + l15];
    for (int tile = blockIdx.x; tile < NN / 32; tile += gridDim.x) {
        const int row0 = tile * 32 + rg * 16;
        const ushort* Ar = A + (size_t)(row0 + l15) * 128 + quad * 8;
        short8 a[K032];
#pragma unroll
        for (int k0 = 0; k0 < K032; k0++) a[k0] = *(const short8*)(Ar + k0 * 32);
        f32x4 acc[4];
#pragma unroll
        for (int tt = 0; tt < 4; tt++) acc[tt] = (f32x4){bv[tt], bv[tt], bv[tt], bv[tt]};
#pragma unroll
        for (int k0 = 0; k0 < K032; k0++)
#pragma unroll
            for (int tt = 0; tt < 4; tt++)
                acc[tt] = __builtin_amdgcn_mfma_f32_16x16x32_bf16(a[k0], breg[tt][k0], acc[tt], 0, 0, 0);
#pragma unroll
        for (int tt = 0; tt < 4; tt++) {
            const int col = (ch * 4 + tt) * 16 + l15;
#pragma unroll
            for (int r = 0; r < 4; r++) {
                ushort v = f2b(acc[tt][r]);
                if (key) v = enc16(v);
                Ch[(size_t)(row0 + quad * 4 + r) * D + col] = v;
            }
        }
    }
}

// ---------------- interleaved multi-relation scatter-max, 8-wide unrolled ----------------
// Up to 8 gathers/relation x G relations in flight per wave; excess lands on the
// L1-hot dummy row (max-neutral key 0). CAPS=16 -> at most 2 outer iterations.
template <int G>
__global__ __launch_bounds__(256) void agg_kernel(const ushort* __restrict__ mb,
                                                  const int* __restrict__ deg,
                                                  const int* __restrict__ slots,
                                                  const int* __restrict__ ovf_cnt,
                                                  const int* __restrict__ ovf,
                                                  int g0,
                                                  const ushort* __restrict__ base,
                                                  ushort* __restrict__ outh,
                                                  int do_relu) {
    const int wv = threadIdx.x >> 6;
    const int lane = threadIdx.x & 63;
    const int node = blockIdx.x * 4 + wv;
    if (node >= NN) return;
    const int DUM = NN * D * 2;  // byte offset of dummy row
    const int* db = deg + (size_t)node * NR + g0;
    const int* sb = slots + ((size_t)node * NR + g0) * CAPS;
    int nd[G], s_l[G];
    const char* ml[G];
#pragma unroll
    for (int g = 0; g < G; g++) {
        int n = db[g];
        nd[g] = (n > CAPS) ? CAPS : n;
        s_l[g] = (lane < nd[g]) ? sb[g * CAPS + lane] : DUM;
        ml[g] = (const char*)(mb + (size_t)g * (NN + 1) * D) + lane * 4;
    }
    int ndmax = 0;
#pragma unroll
    for (int g = 0; g < G; g++) ndmax = (nd[g] > ndmax) ? nd[g] : ndmax;
    u16x2 acc[G];
#pragma unroll
    for (int g = 0; g < G; g++) acc[g] = (u16x2)0;
    for (int i = 0; i < ndmax; i += 8) {
        int s[G][8];
#pragma unroll
        for (int g = 0; g < G; g++) {
#pragma unroll
            for (int u = 0; u < 8; u++) {
                int sv = __shfl(s_l[g], i + u);
                s[g][u] = (i + u < nd[g]) ? sv : DUM;
            }
        }
#pragma unroll
        for (int g = 0; g < G; g++) {
            u16x2 v0 = *(const u16x2*)(ml[g] + s[g][0]);
            u16x2 v1 = *(const u16x2*)(ml[g] + s[g][1]);
            u16x2 v2 = *(const u16x2*)(ml[g] + s[g][2]);
            u16x2 v3 = *(const u16x2*)(ml[g] + s[g][3]);
            u16x2 v4 = *(const u16x2*)(ml[g] + s[g][4]);
            u16x2 v5 = *(const u16x2*)(ml[g] + s[g][5]);
            u16x2 v6 = *(const u16x2*)(ml[g] + s[g][6]);
            u16x2 v7 = *(const u16x2*)(ml[g] + s[g][7]);
            u16x2 m01 = vmax2(v0, v1), m23 = vmax2(v2, v3);
            u16x2 m45 = vmax2(v4, v5), m67 = vmax2(v6, v7);
            acc[g] = vmax2(acc[g], vmax2(vmax2(m01, m23), vmax2(m45, m67)));
        }
    }
    // rare overflow edges (deg > CAPS): wave-uniform scan of tiny list
    int novf = *ovf_cnt;
    if (novf > OVFCAP) novf = OVFCAP;
    for (int i = 0; i < novf; i++) {
        int edr = ovf[2 * i];
        int dr = edr - (node * NR + g0);
        if (dr >= 0 && dr < G) {
            int so = ovf[2 * i + 1];
#pragma unroll
            for (int g = 0; g < G; g++)
                if (dr == g)
                    acc[g] = vmax2(acc[g], *(const u16x2*)(ml[g] + so));
        }
    }
    uint bp = ((const uint*)(base + (size_t)node * D))[lane];
    float rx = __uint_as_float(bp << 16), ry = __uint_as_float(bp & 0xffff0000u);
#pragma unroll
    for (int g = 0; g < G; g++) {
        rx += (nd[g] > 0) ? b2f(dec16(acc[g].x)) : 0.f;
        ry += (nd[g] > 0) ? b2f(dec16(acc[g].y)) : 0.f;
    }
    if (do_relu) { rx = fmaxf(rx, 0.f); ry = fmaxf(ry, 0.f); }
    uint pk = (uint)f2b(rx) | ((uint)f2b(ry) << 16);
    ((uint*)(outh + (size_t)node * D))[lane] = pk;
}

// ---------------- global add pool (batch sorted), h in bf16 ----------------
#define PCH 128
__global__ __launch_bounds__(128) void pool_kernel(const ushort* __restrict__ h,
                                                   const int* __restrict__ batch,
                                                   float* __restrict__ out) {
    int c = threadIdx.x;
    int n0 = blockIdx.x * PCH;
    if (n0 >= NN) return;
    int n1 = n0 + PCH; if (n1 > NN) n1 = NN;
    int cur = batch[n0];
    float acc = 0.f;
    for (int n = n0; n < n1; n++) {
        int g = batch[n];
        if (g != cur) {
            atomicAdd(&out[cur * D + c], acc);
            acc = 0.f;
            cur = g;
        }
        acc += b2f(h[(size_t)n * D + c]);
    }
    atomicAdd(&out[cur * D + c], acc);
}

extern "C" void kernel_launch(void* const* d_in, const int* in_sizes, int n_in,
                              void* d_out, int out_size, void* d_ws, size_t ws_size,
                              hipStream_t stream) {
    const float* x = (const float*)d_in[0];
    const int* ei[4] = {(const int*)d_in[1], (const int*)d_in[2],
                        (const int*)d_in[3], (const int*)d_in[4]};
    const int* batch = (const int*)d_in[5];
    const float* emb_w = (const float*)d_in[6];
    const float* emb_b = (const float*)d_in[7];
    const float* root_w = (const float*)d_in[8];
    const float* root_b = (const float*)d_in[9];
    const float* conv_w = (const float*)d_in[10];
    float* out = (float*)d_out;

    const size_t WPT = (size_t)FIN * 128 + 20 * (size_t)128 * 128;  // permuted weights
    const size_t intWords = (size_t)NR * NN * (1 + CAPS) + 1 + 2 * OVFCAP;
    // choose G by ws capacity (ws_size constant across calls -> same path every launch)
    int G = 1;
    for (int g = 4; g >= 1; g >>= 1) {
        size_t need = ((size_t)NN * D * 2 + (size_t)g * (NN + 1) * D + (size_t)NN * FIN + WPT) * 2 +
                      intWords * 4;
        if (ws_size >= need) { G = g; break; }
    }

    // workspace layout
    ushort* hb = (ushort*)d_ws;                          // NN*D
    ushort* ob = hb + (size_t)NN * D;                    // NN*D (base)
    ushort* mbuf = ob + (size_t)NN * D;                  // G*(NN+1)*D (key16, +dummy row)
    ushort* xb = mbuf + (size_t)G * (NN + 1) * D;        // NN*FIN
    ushort* wp = xb + (size_t)NN * FIN;                  // WPT
    int* deg = (int*)(wp + WPT);                         // NN*NR  (node-major)
    int* ovf_cnt = deg + (size_t)NR * NN;                // 1
    int* slots = ovf_cnt + 1;                            // NN*NR*CAPS (src byte-offsets)
    int* ovf = slots + (size_t)NR * NN * CAPS;           // 2*OVFCAP
    ushort* wpEmb = wp;
    ushort* wpRoot = wp + (size_t)FIN * 128;
    ushort* wpConv = wpRoot + (size_t)4 * 128 * 128;

    // ---- adjacency build: zero deg+ovf_cnt + one-pass partitioned slot fill ----
    zero_i32<<<(NR * NN + 1 + 255) / 256, 256, 0, stream>>>(deg, NR * NN + 1);
    {
        int nch = (NR * NE + EPB - 1) / EPB;
        slot_fill<<<nch * FP, 256, 0, stream>>>(ei[0], ei[1], ei[2], ei[3],
                                                deg, slots, ovf_cnt, ovf);
    }

    // ---- weight permute + input convert + dummy rows ----
    {
        int t1 = FIN * 128;
        wperm_kernel<<<(t1 + 255) / 256, 256, 0, stream>>>(emb_w, wpEmb, FIN, t1);
        int t2 = 4 * 128 * 128;
        wperm_kernel<<<(t2 + 255) / 256, 256, 0, stream>>>(root_w, wpRoot, 128, t2);
        int t3 = 16 * 128 * 128;
        wperm_kernel<<<(t3 + 255) / 256, 256, 0, stream>>>(conv_w, wpConv, 128, t3);
        int t4 = NN * FIN;
        xcvt<<<(t4 + 255) / 256, 256, 0, stream>>>(x, xb, t4);
        zero_dummy<<<(G * D + 255) / 256, 256, 0, stream>>>(mbuf, G);
    }

    // ---- embedding ----
    mgemm<FIN, 0><<<1024, 256, 0, stream>>>(xb, wpEmb, emb_b, hb);

    // ---- layers ----
    for (int l = 0; l < NL; l++) {
        if (G == 4) {
            mgemm5<<<dim3(640, 5), 256, 0, stream>>>(hb, wpRoot + (size_t)l * 128 * 128,
                                                     wpConv + (size_t)l * 4 * 128 * 128,
                                                     root_b + (size_t)l * D, ob, mbuf);
            agg_kernel<4><<<(NN + 3) / 4, 256, 0, stream>>>(mbuf, deg, slots, ovf_cnt, ovf,
                                                            0, ob, hb, 1);
        } else {
            mgemm<128, 0><<<1024, 256, 0, stream>>>(hb, wpRoot + (size_t)l * 128 * 128,
                                                    root_b + (size_t)l * D, ob);
            for (int g0 = 0; g0 < NR; g0 += G) {
                for (int r = g0; r < g0 + G; r++)
                    mgemm<128, 1><<<1024, 256, 0, stream>>>(
                        hb, wpConv + (size_t)(l * NR + r) * 128 * 128, nullptr,
                        mbuf + (size_t)(r - g0) * (NN + 1) * D);
                int last = (g0 + G == NR);
                if (G == 2)
                    agg_kernel<2><<<(NN + 3) / 4, 256, 0, stream>>>(
                        mbuf, deg, slots, ovf_cnt, ovf, g0, ob, last ? hb : ob, last ? 1 : 0);
                else
                    agg_kernel<1><<<(NN + 3) / 4, 256, 0, stream>>>(
                        mbuf, deg, slots, ovf_cnt, ovf, g0, ob, last ? hb : ob, last ? 1 : 0);
            }
        }
    }

    // ---- global add pool ----
    zero_f32<<<(NGR * D + 255) / 256, 256, 0, stream>>>(out, NGR * D);
    pool_kernel<<<(NN + PCH - 1) / PCH, 128, 0, stream>>>(hb, batch, out);
}

// Round 12
// 772.706 us; speedup vs baseline: 1.1302x; 1.0771x over previous
//
#include <hip/hip_runtime.h>

#define NN 100000   // nodes
#define NE 500000   // edges per relation
#define NR 4        // relations
#define NL 4        // layers
#define FIN 64      // input features
#define D 128       // embedding dim
#define NGR 64      // graphs

#define FP 8        // dst partitions (XCD round-robin heuristic)
#define PSZ ((NN + FP - 1) / FP)   // 12500 nodes per partition
#define EPB 4096    // edges per block chunk in slot_fill
#define CAPS 16     // slot capacity; overflow -> tiny global list
#define OVFCAP 8192 // overflow entries (expected ~10; P(deg>16|Poisson(5))~3e-5)

typedef __attribute__((ext_vector_type(8))) short short8;
typedef __attribute__((ext_vector_type(4))) float f32x4;
typedef __attribute__((ext_vector_type(2))) unsigned short u16x2;
typedef unsigned short ushort;
typedef unsigned int uint;

__device__ __forceinline__ ushort f2b(float f) {
    uint u = __float_as_uint(f);
    uint r = (u + 0x7fffu + ((u >> 16) & 1u)) >> 16;  // RNE
    return (ushort)r;
}
__device__ __forceinline__ float b2f(ushort b) {
    return __uint_as_float(((uint)b) << 16);
}
// monotone bf16 -> u16 key (order-isomorphic bijection); key 0 = -inf sentinel
__device__ __forceinline__ ushort enc16(ushort u) {
    return u ^ (ushort)((((short)u) >> 15) | (short)0x8000);
}
__device__ __forceinline__ ushort dec16(ushort k) {
    return k ^ (ushort)((((short)(k ^ 0x8000)) >> 15) | (short)0x8000);
}
__device__ __forceinline__ u16x2 vmax2(u16x2 a, u16x2 b) {
#if __has_builtin(__builtin_elementwise_max)
    return __builtin_elementwise_max(a, b);
#else
    u16x2 r;
    r.x = a.x > b.x ? a.x : b.x;
    r.y = a.y > b.y ? a.y : b.y;
    return r;
#endif
}

// ---------------- utility ----------------
__global__ void zero_i32(int* __restrict__ p, int n) {
    int i = blockIdx.x * blockDim.x + threadIdx.x;
    if (i < n) p[i] = 0;
}
__global__ void zero_f32(float* __restrict__ p, int n) {
    int i = blockIdx.x * blockDim.x + threadIdx.x;
    if (i < n) p[i] = 0.f;
}
__global__ void xcvt(const float* __restrict__ x, ushort* __restrict__ xb, int n) {
    int i = blockIdx.x * blockDim.x + threadIdx.x;
    if (i < n) xb[i] = f2b(x[i]);
}
// zero the dummy row (index NN) of each of the G m-buffers (stride (NN+1)*D)
__global__ void zero_dummy(ushort* __restrict__ mbuf, int G) {
    int i = blockIdx.x * blockDim.x + threadIdx.x;
    if (i < G * D)
        mbuf[(size_t)(i / D) * (NN + 1) * D + (size_t)NN * D + (i % D)] = 0;
}

// W fp32 [nmat][K x 128] -> bf16 MFMA B-fragment order
__global__ void wperm_kernel(const float* __restrict__ W, ushort* __restrict__ dst,
                             int K, int total) {
    int i = blockIdx.x * blockDim.x + threadIdx.x;
    if (i >= total) return;
    int per = K * 128;
    int mi = i / per;
    int o = i - mi * per;
    int j = o & 7, lane = (o >> 3) & 63, rest = o >> 9;
    int K032 = K / 32;
    int k0 = rest % K032, t = rest / K032;
    int k = k0 * 32 + (lane >> 4) * 8 + j;
    int n = t * 16 + (lane & 15);
    dst[i] = f2b(W[(size_t)mi * per + k * 128 + n]);
}

// ---------------- one-pass slotted adjacency build, XCD-partitioned ----------------
// int4 edge loads: 4 independent filter+atomic chains per thread (MLP on the
// ~700cy atomic latency). NE%4==0 so 4-groups never straddle relation arrays.
__global__ __launch_bounds__(256) void slot_fill(const int* __restrict__ e0,
                                                 const int* __restrict__ e1,
                                                 const int* __restrict__ e2,
                                                 const int* __restrict__ e3,
                                                 int* __restrict__ deg,
                                                 int* __restrict__ slots,
                                                 int* __restrict__ ovf_cnt,
                                                 int* __restrict__ ovf) {
    const int part = blockIdx.x % FP;
    const int chunk = blockIdx.x / FP;
    const int plo = part * PSZ;
    const int phi = (plo + PSZ < NN) ? plo + PSZ : NN;
    const int i0 = chunk * EPB;
    int i1 = i0 + EPB; if (i1 > NR * NE) i1 = NR * NE;
    for (int g = i0 + threadIdx.x * 4; g + 4 <= i1; g += 256 * 4) {
        int r = g / NE, j = g - r * NE;
        const int* ei = (r == 0) ? e0 : (r == 1) ? e1 : (r == 2) ? e2 : e3;
        int4 dv = *(const int4*)&ei[NE + j];
        int4 sv = *(const int4*)&ei[j];
        int dd[4] = {dv.x, dv.y, dv.z, dv.w};
        int ss[4] = {sv.x, sv.y, sv.z, sv.w};
#pragma unroll
        for (int u = 0; u < 4; u++) {
            int d = dd[u];
            if (d >= plo && d < phi) {
                int slot = atomicAdd(&deg[d * NR + r], 1);
                if (slot < CAPS) {
                    slots[((size_t)d * NR + r) * CAPS + slot] = ss[u] * (D * 2);
                } else {
                    int oi = atomicAdd(ovf_cnt, 1);
                    if (oi < OVFCAP) {
                        ovf[2 * oi] = d * NR + r;
                        ovf[2 * oi + 1] = ss[u] * (D * 2);
                    }
                }
            }
        }
    }
}

// ---------------- bf16 MFMA GEMM (h rows = operand A; R9-verified layout) ----------------
template <int K, int MODE>
__global__ __launch_bounds__(256) void mgemm(const ushort* __restrict__ A,
                                             const ushort* __restrict__ Bp,
                                             const float* __restrict__ bias,
                                             ushort* __restrict__ Ch) {
    constexpr int K032 = K / 32;
    __shared__ ushort Bs[8 * K032 * 64 * 8];
    const int tid = threadIdx.x;
    for (int i = tid; i < K * 16; i += 256)
        ((float4*)Bs)[i] = ((const float4*)Bp)[i];
    const int lane = tid & 63, wave = tid >> 6;
    const int quad = lane >> 4, l15 = lane & 15;
    const int ch = wave & 1, rg = wave >> 1;
    __syncthreads();
    short8 breg[4][K032];
#pragma unroll
    for (int tt = 0; tt < 4; tt++)
#pragma unroll
        for (int k0 = 0; k0 < K032; k0++)
            breg[tt][k0] = *(const short8*)&Bs[(size_t)(((ch * 4 + tt) * K032 + k0) * 64 + lane) * 8];
    float bv[4] = {0.f, 0.f, 0.f, 0.f};
    if (bias)
#pragma unroll
        for (int tt = 0; tt < 4; tt++) bv[tt] = bias[(ch * 4 + tt) * 16 + l15];
    for (int tile = blockIdx.x; tile < NN / 32; tile += gridDim.x) {
        const int row0 = tile * 32 + rg * 16;
        const ushort* Ar = A + (size_t)(row0 + l15) * K + quad * 8;
        short8 a[K032];
#pragma unroll
        for (int k0 = 0; k0 < K032; k0++) a[k0] = *(const short8*)(Ar + k0 * 32);
        f32x4 acc[4];
#pragma unroll
        for (int tt = 0; tt < 4; tt++) acc[tt] = (f32x4){bv[tt], bv[tt], bv[tt], bv[tt]};
#pragma unroll
        for (int k0 = 0; k0 < K032; k0++)
#pragma unroll
            for (int tt = 0; tt < 4; tt++)
                acc[tt] = __builtin_amdgcn_mfma_f32_16x16x32_bf16(a[k0], breg[tt][k0], acc[tt], 0, 0, 0);
#pragma unroll
        for (int tt = 0; tt < 4; tt++) {
            const int col = (ch * 4 + tt) * 16 + l15;
#pragma unroll
            for (int r = 0; r < 4; r++) {
                ushort v = f2b(acc[tt][r]);
                if (MODE == 1) v = enc16(v);
                Ch[(size_t)(row0 + quad * 4 + r) * D + col] = v;
            }
        }
    }
}

// ---------------- fused per-layer GEMM: blockIdx.y = matrix (0=root, 1..4=conv r) ----------------
__global__ __launch_bounds__(256) void mgemm5(const ushort* __restrict__ A,
                                              const ushort* __restrict__ wpRootL,
                                              const ushort* __restrict__ wpConvL,
                                              const float* __restrict__ biasL,
                                              ushort* __restrict__ ob,
                                              ushort* __restrict__ mbuf) {
    constexpr int K032 = 4;  // K=128
    const int m = blockIdx.y;
    const ushort* Bp = (m == 0) ? wpRootL : wpConvL + (size_t)(m - 1) * 128 * 128;
    ushort* Ch = (m == 0) ? ob : mbuf + (size_t)(m - 1) * (NN + 1) * D;
    const bool key = (m != 0);
    __shared__ ushort Bs[8 * K032 * 64 * 8];
    const int tid = threadIdx.x;
    for (int i = tid; i < 128 * 16; i += 256)
        ((float4*)Bs)[i] = ((const float4*)Bp)[i];
    const int lane = tid & 63, wave = tid >> 6;
    const int quad = lane >> 4, l15 = lane & 15;
    const int ch = wave & 1, rg = wave >> 1;
    __syncthreads();
    short8 breg[4][K032];
#pragma unroll
    for (int tt = 0; tt < 4; tt++)
#pragma unroll
        for (int k0 = 0; k0 < K032; k0++)
            breg[tt][k0] = *(const short8*)&Bs[(size_t)(((ch * 4 + tt) * K032 + k0) * 64 + lane) * 8];
    float bv[4] = {0.f, 0.f, 0.f, 0.f};
    if (m == 0)
#pragma unroll
        for (int tt = 0; tt < 4; tt++) bv[tt] = biasL[(ch * 4 + tt) * 16 + l15];
    for (int tile = blockIdx.x; tile < NN / 32; tile += gridDim.x) {
        const int row0 = tile * 32 + rg * 16;
        const ushort* Ar = A + (size_t)(row0 + l15) * 128 + quad * 8;
        short8 a[K032];
#pragma unroll
        for (int k0 = 0; k0 < K032; k0++) a[k0] = *(const short8*)(Ar + k0 * 32);
        f32x4 acc[4];
#pragma unroll
        for (int tt = 0; tt < 4; tt++) acc[tt] = (f32x4){bv[tt], bv[tt], bv[tt], bv[tt]};
#pragma unroll
        for (int k0 = 0; k0 < K032; k0++)
#pragma unroll
            for (int tt = 0; tt < 4; tt++)
                acc[tt] = __builtin_amdgcn_mfma_f32_16x16x32_bf16(a[k0], breg[tt][k0], acc[tt], 0, 0, 0);
#pragma unroll
        for (int tt = 0; tt < 4; tt++) {
            const int col = (ch * 4 + tt) * 16 + l15;
#pragma unroll
            for (int r = 0; r < 4; r++) {
                ushort v = f2b(acc[tt][r]);
                if (key) v = enc16(v);
                Ch[(size_t)(row0 + quad * 4 + r) * D + col] = v;
            }
        }
    }
}

// ---------------- interleaved multi-relation scatter-max, 8-wide unrolled ----------------
// G=4: one full-wave coalesced load covers the node's entire 64-int slot block
// (relation g, slot i in lane g*16+i). Excess gathers land on L1-hot dummy row.
template <int G>
__global__ __launch_bounds__(256) void agg_kernel(const ushort* __restrict__ mb,
                                                  const int* __restrict__ deg,
                                                  const int* __restrict__ slots,
                                                  const int* __restrict__ ovf_cnt,
                                                  const int* __restrict__ ovf,
                                                  int g0,
                                                  const ushort* __restrict__ base,
                                                  ushort* __restrict__ outh,
                                                  int do_relu) {
    const int wv = threadIdx.x >> 6;
    const int lane = threadIdx.x & 63;
    const int node = blockIdx.x * 4 + wv;
    if (node >= NN) return;
    const int DUM = NN * D * 2;  // byte offset of dummy row
    int nd[G];
    const char* ml[G];
    if (G == 4) {
        int4 d4 = *(const int4*)(deg + (size_t)node * NR);
        int dd[4] = {d4.x, d4.y, d4.z, d4.w};
#pragma unroll
        for (int g = 0; g < G; g++) nd[g] = (dd[g] > CAPS) ? CAPS : dd[g];
    } else {
        const int* db = deg + (size_t)node * NR + g0;
#pragma unroll
        for (int g = 0; g < G; g++) {
            int n = db[g];
            nd[g] = (n > CAPS) ? CAPS : n;
        }
    }
#pragma unroll
    for (int g = 0; g < G; g++)
        ml[g] = (const char*)(mb + (size_t)g * (NN + 1) * D) + lane * 4;
    // one coalesced 64-lane load: lane = g*CAPS + slot  (CAPS==16, G<=4)
    int s_all = (lane < G * CAPS)
                    ? slots[((size_t)node * NR + g0) * CAPS + lane]
                    : DUM;
    int ndmax = 0;
#pragma unroll
    for (int g = 0; g < G; g++) ndmax = (nd[g] > ndmax) ? nd[g] : ndmax;
    u16x2 acc[G];
#pragma unroll
    for (int g = 0; g < G; g++) acc[g] = (u16x2)0;
    for (int i = 0; i < ndmax; i += 8) {
        int s[G][8];
#pragma unroll
        for (int g = 0; g < G; g++) {
#pragma unroll
            for (int u = 0; u < 8; u++) {
                int sv = __shfl(s_all, g * CAPS + i + u);
                s[g][u] = (i + u < nd[g]) ? sv : DUM;
            }
        }
#pragma unroll
        for (int g = 0; g < G; g++) {
            u16x2 v0 = *(const u16x2*)(ml[g] + s[g][0]);
            u16x2 v1 = *(const u16x2*)(ml[g] + s[g][1]);
            u16x2 v2 = *(const u16x2*)(ml[g] + s[g][2]);
            u16x2 v3 = *(const u16x2*)(ml[g] + s[g][3]);
            u16x2 v4 = *(const u16x2*)(ml[g] + s[g][4]);
            u16x2 v5 = *(const u16x2*)(ml[g] + s[g][5]);
            u16x2 v6 = *(const u16x2*)(ml[g] + s[g][6]);
            u16x2 v7 = *(const u16x2*)(ml[g] + s[g][7]);
            u16x2 m01 = vmax2(v0, v1), m23 = vmax2(v2, v3);
            u16x2 m45 = vmax2(v4, v5), m67 = vmax2(v6, v7);
            acc[g] = vmax2(acc[g], vmax2(vmax2(m01, m23), vmax2(m45, m67)));
        }
    }
    // rare overflow edges (deg > CAPS): wave-uniform scan of tiny list
    int novf = *ovf_cnt;
    if (novf > OVFCAP) novf = OVFCAP;
    for (int i = 0; i < novf; i++) {
        int edr = ovf[2 * i];
        int dr = edr - (node * NR + g0);
        if (dr >= 0 && dr < G) {
            int so = ovf[2 * i + 1];
#pragma unroll
            for (int g = 0; g < G; g++)
                if (dr == g)
                    acc[g] = vmax2(acc[g], *(const u16x2*)(ml[g] + so));
        }
    }
    uint bp = ((const uint*)(base + (size_t)node * D))[lane];
    float rx = __uint_as_float(bp << 16), ry = __uint_as_float(bp & 0xffff0000u);
#pragma unroll
    for (int g = 0; g < G; g++) {
        rx += (nd[g] > 0) ? b2f(dec16(acc[g].x)) : 0.f;
        ry += (nd[g] > 0) ? b2f(dec16(acc[g].y)) : 0.f;
    }
    if (do_relu) { rx = fmaxf(rx, 0.f); ry = fmaxf(ry, 0.f); }
    uint pk = (uint)f2b(rx) | ((uint)f2b(ry) << 16);
    ((uint*)(outh + (size_t)node * D))[lane] = pk;
}

// ---------------- global add pool (batch sorted), h in bf16 ----------------
#define PCH 128
__global__ __launch_bounds__(128) void pool_kernel(const ushort* __restrict__ h,
                                                   const int* __restrict__ batch,
                                                   float* __restrict__ out) {
    int c = threadIdx.x;
    int n0 = blockIdx.x * PCH;
    if (n0 >= NN) return;
    int n1 = n0 + PCH; if (n1 > NN) n1 = NN;
    int cur = batch[n0];
    float acc = 0.f;
    for (int n = n0; n < n1; n++) {
        int g = batch[n];
        if (g != cur) {
            atomicAdd(&out[cur * D + c], acc);
            acc = 0.f;
            cur = g;
        }
        acc += b2f(h[(size_t)n * D + c]);
    }
    atomicAdd(&out[cur * D + c], acc);
}

extern "C" void kernel_launch(void* const* d_in, const int* in_sizes, int n_in,
                              void* d_out, int out_size, void* d_ws, size_t ws_size,
                              hipStream_t stream) {
    const float* x = (const float*)d_in[0];
    const int* ei[4] = {(const int*)d_in[1], (const int*)d_in[2],
                        (const int*)d_in[3], (const int*)d_in[4]};
    const int* batch = (const int*)d_in[5];
    const float* emb_w = (const float*)d_in[6];
    const float* emb_b = (const float*)d_in[7];
    const float* root_w = (const float*)d_in[8];
    const float* root_b = (const float*)d_in[9];
    const float* conv_w = (const float*)d_in[10];
    float* out = (float*)d_out;

    const size_t WPT = (size_t)FIN * 128 + 20 * (size_t)128 * 128;  // permuted weights
    const size_t intWords = (size_t)NR * NN * (1 + CAPS) + 1 + 2 * OVFCAP;
    // choose G by ws capacity (ws_size constant across calls -> same path every launch)
    int G = 1;
    for (int g = 4; g >= 1; g >>= 1) {
        size_t need = ((size_t)NN * D * 2 + (size_t)g * (NN + 1) * D + (size_t)NN * FIN + WPT) * 2 +
                      intWords * 4;
        if (ws_size >= need) { G = g; break; }
    }

    // workspace layout
    ushort* hb = (ushort*)d_ws;                          // NN*D
    ushort* ob = hb + (size_t)NN * D;                    // NN*D (base)
    ushort* mbuf = ob + (size_t)NN * D;                  // G*(NN+1)*D (key16, +dummy row)
    ushort* xb = mbuf + (size_t)G * (NN + 1) * D;        // NN*FIN
    ushort* wp = xb + (size_t)NN * FIN;                  // WPT
    int* deg = (int*)(wp + WPT);                         // NN*NR  (node-major)
    int* ovf_cnt = deg + (size_t)NR * NN;                // 1
    int* slots = ovf_cnt + 1;                            // NN*NR*CAPS (src byte-offsets)
    int* ovf = slots + (size_t)NR * NN * CAPS;           // 2*OVFCAP
    ushort* wpEmb = wp;
    ushort* wpRoot = wp + (size_t)FIN * 128;
    ushort* wpConv = wpRoot + (size_t)4 * 128 * 128;

    // ---- adjacency build: zero deg+ovf_cnt + one-pass partitioned slot fill ----
    zero_i32<<<(NR * NN + 1 + 255) / 256, 256, 0, stream>>>(deg, NR * NN + 1);
    {
        int nch = (NR * NE + EPB - 1) / EPB;
        slot_fill<<<nch * FP, 256, 0, stream>>>(ei[0], ei[1], ei[2], ei[3],
                                                deg, slots, ovf_cnt, ovf);
    }

    // ---- weight permute + input convert + dummy rows ----
    {
        int t1 = FIN * 128;
        wperm_kernel<<<(t1 + 255) / 256, 256, 0, stream>>>(emb_w, wpEmb, FIN, t1);
        int t2 = 4 * 128 * 128;
        wperm_kernel<<<(t2 + 255) / 256, 256, 0, stream>>>(root_w, wpRoot, 128, t2);
        int t3 = 16 * 128 * 128;
        wperm_kernel<<<(t3 + 255) / 256, 256, 0, stream>>>(conv_w, wpConv, 128, t3);
        int t4 = NN * FIN;
        xcvt<<<(t4 + 255) / 256, 256, 0, stream>>>(x, xb, t4);
        zero_dummy<<<(G * D + 255) / 256, 256, 0, stream>>>(mbuf, G);
    }

    // ---- embedding ----
    mgemm<FIN, 0><<<1024, 256, 0, stream>>>(xb, wpEmb, emb_b, hb);

    // ---- layers ----
    for (int l = 0; l < NL; l++) {
        if (G == 4) {
            mgemm5<<<dim3(640, 5), 256, 0, stream>>>(hb, wpRoot + (size_t)l * 128 * 128,
                                                     wpConv + (size_t)l * 4 * 128 * 128,
                                                     root_b + (size_t)l * D, ob, mbuf);
            agg_kernel<4><<<(NN + 3) / 4, 256, 0, stream>>>(mbuf, deg, slots, ovf_cnt, ovf,
                                                            0, ob, hb, 1);
        } else {
            mgemm<128, 0><<<1024, 256, 0, stream>>>(hb, wpRoot + (size_t)l * 128 * 128,
                                                    root_b + (size_t)l * D, ob);
            for (int g0 = 0; g0 < NR; g0 += G) {
                for (int r = g0; r < g0 + G; r++)
                    mgemm<128, 1><<<1024, 256, 0, stream>>>(
                        hb, wpConv + (size_t)(l * NR + r) * 128 * 128, nullptr,
                        mbuf + (size_t)(r - g0) * (NN + 1) * D);
                int last = (g0 + G == NR);
                if (G == 2)
                    agg_kernel<2><<<(NN + 3) / 4, 256, 0, stream>>>(
                        mbuf, deg, slots, ovf_cnt, ovf, g0, ob, last ? hb : ob, last ? 1 : 0);
                else
                    agg_kernel<1><<<(NN + 3) / 4, 256, 0, stream>>>(
                        mbuf, deg, slots, ovf_cnt, ovf, g0, ob, last ? hb : ob, last ? 1 : 0);
            }
        }
    }

    // ---- global add pool ----
    zero_f32<<<(NGR * D + 255) / 256, 256, 0, stream>>>(out, NGR * D);
    pool_kernel<<<(NN + PCH - 1) / PCH, 128, 0, stream>>>(hb, batch, out);
}

// Round 13
// 759.094 us; speedup vs baseline: 1.1505x; 1.0179x over previous
//
#include <hip/hip_runtime.h>

#define NN 100000   // nodes
#define NE 500000   // edges per relation
#define NR 4        // relations
#define NL 4        // layers
#define FIN 64      // input features
#define D 128       // embedding dim
#define NGR 64      // graphs

#define FP 8        // dst partitions (XCD round-robin heuristic)
#define PSZ ((NN + FP - 1) / FP)   // 12500 nodes per partition
#define CAPS 16     // slot capacity; overflow -> tiny global list
#define OVFCAP 8192 // overflow entries (expected ~10)

#define EPB2 2048                             // edges per slot-fill block (256 thr x 8)
#define SFCH ((NR * NE + EPB2 - 1) / EPB2)    // 977 chunks
#define SFB (SFCH * FP)                       // slot-fill blocks
#define AUXB 512                              // aux (wperm/xcvt/dummy) blocks

typedef __attribute__((ext_vector_type(8))) short short8;
typedef __attribute__((ext_vector_type(4))) float f32x4;
typedef __attribute__((ext_vector_type(2))) unsigned short u16x2;
typedef unsigned short ushort;
typedef unsigned int uint;

__device__ __forceinline__ ushort f2b(float f) {
    uint u = __float_as_uint(f);
    uint r = (u + 0x7fffu + ((u >> 16) & 1u)) >> 16;  // RNE
    return (ushort)r;
}
__device__ __forceinline__ float b2f(ushort b) {
    return __uint_as_float(((uint)b) << 16);
}
// monotone bf16 -> u16 key (order-isomorphic bijection); key 0 = -inf sentinel
__device__ __forceinline__ ushort enc16(ushort u) {
    return u ^ (ushort)((((short)u) >> 15) | (short)0x8000);
}
__device__ __forceinline__ ushort dec16(ushort k) {
    return k ^ (ushort)((((short)(k ^ 0x8000)) >> 15) | (short)0x8000);
}
__device__ __forceinline__ u16x2 vmax2(u16x2 a, u16x2 b) {
#if __has_builtin(__builtin_elementwise_max)
    return __builtin_elementwise_max(a, b);
#else
    u16x2 r;
    r.x = a.x > b.x ? a.x : b.x;
    r.y = a.y > b.y ? a.y : b.y;
    return r;
#endif
}

// ---------------- utility ----------------
__global__ void zero_i32(int* __restrict__ p, int n) {
    int i = blockIdx.x * blockDim.x + threadIdx.x;
    if (i < n) p[i] = 0;
}
__global__ void zero_f32(float* __restrict__ p, int n) {
    int i = blockIdx.x * blockDim.x + threadIdx.x;
    if (i < n) p[i] = 0.f;
}

__device__ __forceinline__ void wperm_elem(const float* __restrict__ W,
                                           ushort* __restrict__ dst, int K, int i) {
    int per = K * 128;
    int mi = i / per;
    int o = i - mi * per;
    int j = o & 7, lane = (o >> 3) & 63, rest = o >> 9;
    int K032 = K / 32;
    int k0 = rest % K032, t = rest / K032;
    int k = k0 * 32 + (lane >> 4) * 8 + j;
    int n = t * 16 + (lane & 15);
    dst[i] = f2b(W[(size_t)mi * per + k * 128 + n]);
}

// ---------------- übernel: aux (wperm/xcvt/dummy) blocks + slot_fill blocks ----------------
// Aux blocks come FIRST so they co-reside with slot_fill's full lifetime,
// filling its idle VALU/memory issue slots (slot_fill: VALUBusy 7%, HBM 23%).
__global__ __launch_bounds__(256) void build_kernel(
    const int* __restrict__ e0, const int* __restrict__ e1,
    const int* __restrict__ e2, const int* __restrict__ e3,
    int* __restrict__ deg, int* __restrict__ slots,
    int* __restrict__ ovf_cnt, int* __restrict__ ovf,
    const float* __restrict__ x, ushort* __restrict__ xb,
    const float* __restrict__ emb_w, const float* __restrict__ root_w,
    const float* __restrict__ conv_w,
    ushort* __restrict__ wpEmb, ushort* __restrict__ wpRoot,
    ushort* __restrict__ wpConv, ushort* __restrict__ mbuf, int G) {
    if (blockIdx.x < AUXB) {
        const int T1 = FIN * 128;          // emb wperm
        const int T2 = 4 * 128 * 128;      // root wperm
        const int T3 = 16 * 128 * 128;     // conv wperm
        const int T4 = NN * FIN;           // xcvt
        const int T5 = G * D;              // dummy rows
        const int total = T1 + T2 + T3 + T4 + T5;
        for (int i = blockIdx.x * 256 + threadIdx.x; i < total; i += AUXB * 256) {
            if (i < T1) wperm_elem(emb_w, wpEmb, FIN, i);
            else if (i < T1 + T2) wperm_elem(root_w, wpRoot, 128, i - T1);
            else if (i < T1 + T2 + T3) wperm_elem(conv_w, wpConv, 128, i - T1 - T2);
            else if (i < T1 + T2 + T3 + T4) {
                int k = i - T1 - T2 - T3;
                xb[k] = f2b(x[k]);
            } else {
                int k = i - T1 - T2 - T3 - T4;
                mbuf[(size_t)(k / D) * (NN + 1) * D + (size_t)NN * D + (k % D)] = 0;
            }
        }
        return;
    }
    // ---- slot_fill: 8 independent filter+atomic chains per thread ----
    const int b = blockIdx.x - AUXB;
    const int part = b % FP;
    const int chunk = b / FP;
    const int plo = part * PSZ;
    const int phi = (plo + PSZ < NN) ? plo + PSZ : NN;
    int g = chunk * EPB2 + threadIdx.x * 8;
    if (g + 8 > NR * NE) return;  // NE%8==0 -> no partial groups
    int r = (g >= 3 * NE) ? 3 : (g >= 2 * NE) ? 2 : (g >= NE) ? 1 : 0;
    int j = g - r * NE;
    const int* ei = (r == 0) ? e0 : (r == 1) ? e1 : (r == 2) ? e2 : e3;
    int4 dv0 = *(const int4*)&ei[NE + j];
    int4 dv1 = *(const int4*)&ei[NE + j + 4];
    int4 sv0 = *(const int4*)&ei[j];
    int4 sv1 = *(const int4*)&ei[j + 4];
    int dd[8] = {dv0.x, dv0.y, dv0.z, dv0.w, dv1.x, dv1.y, dv1.z, dv1.w};
    int ss[8] = {sv0.x, sv0.y, sv0.z, sv0.w, sv1.x, sv1.y, sv1.z, sv1.w};
#pragma unroll
    for (int u = 0; u < 8; u++) {
        int d = dd[u];
        if (d >= plo && d < phi) {
            int slot = atomicAdd(&deg[d * NR + r], 1);
            if (slot < CAPS) {
                slots[((size_t)d * NR + r) * CAPS + slot] = ss[u] * (D * 2);
            } else {
                int oi = atomicAdd(ovf_cnt, 1);
                if (oi < OVFCAP) {
                    ovf[2 * oi] = d * NR + r;
                    ovf[2 * oi + 1] = ss[u] * (D * 2);
                }
            }
        }
    }
}

// ---------------- bf16 MFMA GEMM (h rows = operand A; R9-verified layout) ----------------
template <int K, int MODE>
__global__ __launch_bounds__(256) void mgemm(const ushort* __restrict__ A,
                                             const ushort* __restrict__ Bp,
                                             const float* __restrict__ bias,
                                             ushort* __restrict__ Ch) {
    constexpr int K032 = K / 32;
    __shared__ ushort Bs[8 * K032 * 64 * 8];
    const int tid = threadIdx.x;
    for (int i = tid; i < K * 16; i += 256)
        ((float4*)Bs)[i] = ((const float4*)Bp)[i];
    const int lane = tid & 63, wave = tid >> 6;
    const int quad = lane >> 4, l15 = lane & 15;
    const int ch = wave & 1, rg = wave >> 1;
    __syncthreads();
    short8 breg[4][K032];
#pragma unroll
    for (int tt = 0; tt < 4; tt++)
#pragma unroll
        for (int k0 = 0; k0 < K032; k0++)
            breg[tt][k0] = *(const short8*)&Bs[(size_t)(((ch * 4 + tt) * K032 + k0) * 64 + lane) * 8];
    float bv[4] = {0.f, 0.f, 0.f, 0.f};
    if (bias)
#pragma unroll
        for (int tt = 0; tt < 4; tt++) bv[tt] = bias[(ch * 4 + tt) * 16 + l15];
    for (int tile = blockIdx.x; tile < NN / 32; tile += gridDim.x) {
        const int row0 = tile * 32 + rg * 16;
        const ushort* Ar = A + (size_t)(row0 + l15) * K + quad * 8;
        short8 a[K032];
#pragma unroll
        for (int k0 = 0; k0 < K032; k0++) a[k0] = *(const short8*)(Ar + k0 * 32);
        f32x4 acc[4];
#pragma unroll
        for (int tt = 0; tt < 4; tt++) acc[tt] = (f32x4){bv[tt], bv[tt], bv[tt], bv[tt]};
#pragma unroll
        for (int k0 = 0; k0 < K032; k0++)
#pragma unroll
            for (int tt = 0; tt < 4; tt++)
                acc[tt] = __builtin_amdgcn_mfma_f32_16x16x32_bf16(a[k0], breg[tt][k0], acc[tt], 0, 0, 0);
#pragma unroll
        for (int tt = 0; tt < 4; tt++) {
            const int col = (ch * 4 + tt) * 16 + l15;
#pragma unroll
            for (int r = 0; r < 4; r++) {
                ushort v = f2b(acc[tt][r]);
                if (MODE == 1) v = enc16(v);
                Ch[(size_t)(row0 + quad * 4 + r) * D + col] = v;
            }
        }
    }
}

// ---------------- fused per-layer GEMM: blockIdx.y = matrix (0=root, 1..4=conv r) ----------------
__global__ __launch_bounds__(256) void mgemm5(const ushort* __restrict__ A,
                                              const ushort* __restrict__ wpRootL,
                                              const ushort* __restrict__ wpConvL,
                                              const float* __restrict__ biasL,
                                              ushort* __restrict__ ob,
                                              ushort* __restrict__ mbuf) {
    constexpr int K032 = 4;  // K=128
    const int m = blockIdx.y;
    const ushort* Bp = (m == 0) ? wpRootL : wpConvL + (size_t)(m - 1) * 128 * 128;
    ushort* Ch = (m == 0) ? ob : mbuf + (size_t)(m - 1) * (NN + 1) * D;
    const bool key = (m != 0);
    __shared__ ushort Bs[8 * K032 * 64 * 8];
    const int tid = threadIdx.x;
    for (int i = tid; i < 128 * 16; i += 256)
        ((float4*)Bs)[i] = ((const float4*)Bp)[i];
    const int lane = tid & 63, wave = tid >> 6;
    const int quad = lane >> 4, l15 = lane & 15;
    const int ch = wave & 1, rg = wave >> 1;
    __syncthreads();
    short8 breg[4][K032];
#pragma unroll
    for (int tt = 0; tt < 4; tt++)
#pragma unroll
        for (int k0 = 0; k0 < K032; k0++)
            breg[tt][k0] = *(const short8*)&Bs[(size_t)(((ch * 4 + tt) * K032 + k0) * 64 + lane) * 8];
    float bv[4] = {0.f, 0.f, 0.f, 0.f};
    if (m == 0)
#pragma unroll
        for (int tt = 0; tt < 4; tt++) bv[tt] = biasL[(ch * 4 + tt) * 16 + l15];
    for (int tile = blockIdx.x; tile < NN / 32; tile += gridDim.x) {
        const int row0 = tile * 32 + rg * 16;
        const ushort* Ar = A + (size_t)(row0 + l15) * 128 + quad * 8;
        short8 a[K032];
#pragma unroll
        for (int k0 = 0; k0 < K032; k0++) a[k0] = *(const short8*)(Ar + k0 * 32);
        f32x4 acc[4];
#pragma unroll
        for (int tt = 0; tt < 4; tt++) acc[tt] = (f32x4){bv[tt], bv[tt], bv[tt], bv[tt]};
#pragma unroll
        for (int k0 = 0; k0 < K032; k0++)
#pragma unroll
            for (int tt = 0; tt < 4; tt++)
                acc[tt] = __builtin_amdgcn_mfma_f32_16x16x32_bf16(a[k0], breg[tt][k0], acc[tt], 0, 0, 0);
#pragma unroll
        for (int tt = 0; tt < 4; tt++) {
            const int col = (ch * 4 + tt) * 16 + l15;
#pragma unroll
            for (int r = 0; r < 4; r++) {
                ushort v = f2b(acc[tt][r]);
                if (key) v = enc16(v);
                Ch[(size_t)(row0 + quad * 4 + r) * D + col] = v;
            }
        }
    }
}

// ---------------- interleaved multi-relation scatter-max, 8-wide unrolled ----------------
template <int G>
__global__ __launch_bounds__(256) void agg_kernel(const ushort* __restrict__ mb,
                                                  const int* __restrict__ deg,
                                                  const int* __restrict__ slots,
                                                  const int* __restrict__ ovf_cnt,
                                                  const int* __restrict__ ovf,
                                                  int g0,
                                                  const ushort* __restrict__ base,
                                                  ushort* __restrict__ outh,
                                                  int do_relu) {
    const int wv = threadIdx.x >> 6;
    const int lane = threadIdx.x & 63;
    const int node = blockIdx.x * 4 + wv;
    if (node >= NN) return;
    const int DUM = NN * D * 2;  // byte offset of dummy row
    int nd[G];
    const char* ml[G];
    if (G == 4) {
        int4 d4 = *(const int4*)(deg + (size_t)node * NR);
        int dd[4] = {d4.x, d4.y, d4.z, d4.w};
#pragma unroll
        for (int g = 0; g < G; g++) nd[g] = (dd[g] > CAPS) ? CAPS : dd[g];
    } else {
        const int* db = deg + (size_t)node * NR + g0;
#pragma unroll
        for (int g = 0; g < G; g++) {
            int n = db[g];
            nd[g] = (n > CAPS) ? CAPS : n;
        }
    }
#pragma unroll
    for (int g = 0; g < G; g++)
        ml[g] = (const char*)(mb + (size_t)g * (NN + 1) * D) + lane * 4;
    int s_all = (lane < G * CAPS)
                    ? slots[((size_t)node * NR + g0) * CAPS + lane]
                    : DUM;
    int ndmax = 0;
#pragma unroll
    for (int g = 0; g < G; g++) ndmax = (nd[g] > ndmax) ? nd[g] : ndmax;
    u16x2 acc[G];
#pragma unroll
    for (int g = 0; g < G; g++) acc[g] = (u16x2)0;
    for (int i = 0; i < ndmax; i += 8) {
        int s[G][8];
#pragma unroll
        for (int g = 0; g < G; g++) {
#pragma unroll
            for (int u = 0; u < 8; u++) {
                int sv = __shfl(s_all, g * CAPS + i + u);
                s[g][u] = (i + u < nd[g]) ? sv : DUM;
            }
        }
#pragma unroll
        for (int g = 0; g < G; g++) {
            u16x2 v0 = *(const u16x2*)(ml[g] + s[g][0]);
            u16x2 v1 = *(const u16x2*)(ml[g] + s[g][1]);
            u16x2 v2 = *(const u16x2*)(ml[g] + s[g][2]);
            u16x2 v3 = *(const u16x2*)(ml[g] + s[g][3]);
            u16x2 v4 = *(const u16x2*)(ml[g] + s[g][4]);
            u16x2 v5 = *(const u16x2*)(ml[g] + s[g][5]);
            u16x2 v6 = *(const u16x2*)(ml[g] + s[g][6]);
            u16x2 v7 = *(const u16x2*)(ml[g] + s[g][7]);
            u16x2 m01 = vmax2(v0, v1), m23 = vmax2(v2, v3);
            u16x2 m45 = vmax2(v4, v5), m67 = vmax2(v6, v7);
            acc[g] = vmax2(acc[g], vmax2(vmax2(m01, m23), vmax2(m45, m67)));
        }
    }
    // rare overflow edges (deg > CAPS): wave-uniform scan of tiny list
    int novf = *ovf_cnt;
    if (novf > OVFCAP) novf = OVFCAP;
    for (int i = 0; i < novf; i++) {
        int edr = ovf[2 * i];
        int dr = edr - (node * NR + g0);
        if (dr >= 0 && dr < G) {
            int so = ovf[2 * i + 1];
#pragma unroll
            for (int g = 0; g < G; g++)
                if (dr == g)
                    acc[g] = vmax2(acc[g], *(const u16x2*)(ml[g] + so));
        }
    }
    uint bp = ((const uint*)(base + (size_t)node * D))[lane];
    float rx = __uint_as_float(bp << 16), ry = __uint_as_float(bp & 0xffff0000u);
#pragma unroll
    for (int g = 0; g < G; g++) {
        rx += (nd[g] > 0) ? b2f(dec16(acc[g].x)) : 0.f;
        ry += (nd[g] > 0) ? b2f(dec16(acc[g].y)) : 0.f;
    }
    if (do_relu) { rx = fmaxf(rx, 0.f); ry = fmaxf(ry, 0.f); }
    uint pk = (uint)f2b(rx) | ((uint)f2b(ry) << 16);
    ((uint*)(outh + (size_t)node * D))[lane] = pk;
}

// ---------------- global add pool (batch sorted), h in bf16 ----------------
#define PCH 128
__global__ __launch_bounds__(128) void pool_kernel(const ushort* __restrict__ h,
                                                   const int* __restrict__ batch,
                                                   float* __restrict__ out) {
    int c = threadIdx.x;
    int n0 = blockIdx.x * PCH;
    if (n0 >= NN) return;
    int n1 = n0 + PCH; if (n1 > NN) n1 = NN;
    int cur = batch[n0];
    float acc = 0.f;
    for (int n = n0; n < n1; n++) {
        int g = batch[n];
        if (g != cur) {
            atomicAdd(&out[cur * D + c], acc);
            acc = 0.f;
            cur = g;
        }
        acc += b2f(h[(size_t)n * D + c]);
    }
    atomicAdd(&out[cur * D + c], acc);
}

extern "C" void kernel_launch(void* const* d_in, const int* in_sizes, int n_in,
                              void* d_out, int out_size, void* d_ws, size_t ws_size,
                              hipStream_t stream) {
    const float* x = (const float*)d_in[0];
    const int* ei[4] = {(const int*)d_in[1], (const int*)d_in[2],
                        (const int*)d_in[3], (const int*)d_in[4]};
    const int* batch = (const int*)d_in[5];
    const float* emb_w = (const float*)d_in[6];
    const float* emb_b = (const float*)d_in[7];
    const float* root_w = (const float*)d_in[8];
    const float* root_b = (const float*)d_in[9];
    const float* conv_w = (const float*)d_in[10];
    float* out = (float*)d_out;

    const size_t WPT = (size_t)FIN * 128 + 20 * (size_t)128 * 128;  // permuted weights
    const size_t intWords = (size_t)NR * NN * (1 + CAPS) + 1 + 2 * OVFCAP;
    // choose G by ws capacity (ws_size constant across calls -> same path every launch)
    int G = 1;
    for (int g = 4; g >= 1; g >>= 1) {
        size_t need = ((size_t)NN * D * 2 + (size_t)g * (NN + 1) * D + (size_t)NN * FIN + WPT) * 2 +
                      intWords * 4;
        if (ws_size >= need) { G = g; break; }
    }

    // workspace layout
    ushort* hb = (ushort*)d_ws;                          // NN*D
    ushort* ob = hb + (size_t)NN * D;                    // NN*D (base)
    ushort* mbuf = ob + (size_t)NN * D;                  // G*(NN+1)*D (key16, +dummy row)
    ushort* xb = mbuf + (size_t)G * (NN + 1) * D;        // NN*FIN
    ushort* wp = xb + (size_t)NN * FIN;                  // WPT
    int* deg = (int*)(wp + WPT);                         // NN*NR  (node-major)
    int* ovf_cnt = deg + (size_t)NR * NN;                // 1
    int* slots = ovf_cnt + 1;                            // NN*NR*CAPS (src byte-offsets)
    int* ovf = slots + (size_t)NR * NN * CAPS;           // 2*OVFCAP
    ushort* wpEmb = wp;
    ushort* wpRoot = wp + (size_t)FIN * 128;
    ushort* wpConv = wpRoot + (size_t)4 * 128 * 128;

    // ---- zero deg+ovf_cnt, then fused build übernel (aux + slot_fill) ----
    zero_i32<<<(NR * NN + 1 + 255) / 256, 256, 0, stream>>>(deg, NR * NN + 1);
    build_kernel<<<AUXB + SFB, 256, 0, stream>>>(ei[0], ei[1], ei[2], ei[3],
                                                 deg, slots, ovf_cnt, ovf,
                                                 x, xb, emb_w, root_w, conv_w,
                                                 wpEmb, wpRoot, wpConv, mbuf, G);

    // ---- embedding ----
    mgemm<FIN, 0><<<1024, 256, 0, stream>>>(xb, wpEmb, emb_b, hb);

    // ---- layers ----
    for (int l = 0; l < NL; l++) {
        if (G == 4) {
            mgemm5<<<dim3(640, 5), 256, 0, stream>>>(hb, wpRoot + (size_t)l * 128 * 128,
                                                     wpConv + (size_t)l * 4 * 128 * 128,
                                                     root_b + (size_t)l * D, ob, mbuf);
            agg_kernel<4><<<(NN + 3) / 4, 256, 0, stream>>>(mbuf, deg, slots, ovf_cnt, ovf,
                                                            0, ob, hb, 1);
        } else {
            mgemm<128, 0><<<1024, 256, 0, stream>>>(hb, wpRoot + (size_t)l * 128 * 128,
                                                    root_b + (size_t)l * D, ob);
            for (int g0 = 0; g0 < NR; g0 += G) {
                for (int r = g0; r < g0 + G; r++)
                    mgemm<128, 1><<<1024, 256, 0, stream>>>(
                        hb, wpConv + (size_t)(l * NR + r) * 128 * 128, nullptr,
                        mbuf + (size_t)(r - g0) * (NN + 1) * D);
                int last = (g0 + G == NR);
                if (G == 2)
                    agg_kernel<2><<<(NN + 3) / 4, 256, 0, stream>>>(
                        mbuf, deg, slots, ovf_cnt, ovf, g0, ob, last ? hb : ob, last ? 1 : 0);
                else
                    agg_kernel<1><<<(NN + 3) / 4, 256, 0, stream>>>(
                        mbuf, deg, slots, ovf_cnt, ovf, g0, ob, last ? hb : ob, last ? 1 : 0);
            }
        }
    }

    // ---- global add pool ----
    zero_f32<<<(NGR * D + 255) / 256, 256, 0, stream>>>(out, NGR * D);
    pool_kernel<<<(NN + PCH - 1) / PCH, 128, 0, stream>>>(hb, batch, out);
}